// Round 4
// baseline (104.059 us; speedup 1.0000x reference)
//
#include <hip/hip_runtime.h>
#include <hip/hip_cooperative_groups.h>
#include <math.h>

#ifndef M_PI
#define M_PI 3.14159265358979323846
#endif

#define NPTS 8192
#define KCOMP 64
#define NBIN 150          // bins of width 0.08 over [-6, 6]
#define XMIN -6.0f
#define BINW_INV 12.5f    // 1/0.08
#define NBLK 256          // 1 block per CU
#define NTHR 1024         // 16 waves
// kern = exp(-8192 d^2): underflows to 0.0f for d > 0.112; at d=0.08 it is
// 1.8e-23 (< 1 ulp of the per-point sum). Bin windowing at +-1 bin omits only
// pairs with d > 0.08 -> numerically exact vs the f32 reference.
//
// Round-4 design: single COOPERATIVE dispatch. Every block redundantly
// counting-sorts all 8192 x's into its own LDS (32 KB), evaluates its 32
// points' windows, writes one partial to ws[bid] (overwriting poison),
// grid.sync(), block 0 reduces 256 partials and plain-stores out[0].
// No memset node, no global atomics -> deterministic, poison-immune.
// Scan is a barrier-free wave-0 shfl scan (was 16 barriers); softmax runs
// concurrently in wave 1. Block barriers: 21 -> 5.

namespace cg = cooperative_groups;

// Single-instruction hardware exp2 (v_exp_f32).
__device__ __forceinline__ float fexp2(float a) {
#if __has_builtin(__builtin_amdgcn_exp2f)
  return __builtin_amdgcn_exp2f(a);
#else
  float r;
  asm("v_exp_f32 %0, %1" : "=v"(r) : "v"(a));
  return r;
#endif
}

__global__ __launch_bounds__(NTHR) void gmm_kernel(
    const float* __restrict__ x,
    const float* __restrict__ logits,
    const float* __restrict__ means,
    const float* __restrict__ log_vars,
    float* __restrict__ ws,
    float* __restrict__ out) {
  __shared__ alignas(16) float xs[NPTS];   // bin-sorted, UNSCALED (32 KB)
  __shared__ int hist[NBIN];
  __shared__ int ofs[NBIN];
  __shared__ int bst[NBIN + 2];
  __shared__ float sa[KCOMP], sq[KCOMP], smn[KCOMP];
  __shared__ float wsum[16];

  const int t = threadIdx.x;

  // ---- phase 1: block-local counting sort of ALL 8192 points ----
  float xv[8];
  int bn[8];
#pragma unroll
  for (int r = 0; r < 8; ++r) xv[r] = x[t + r * NTHR];
  if (t < NBIN) hist[t] = 0;
  __syncthreads();                                    // B1
#pragma unroll
  for (int r = 0; r < 8; ++r) {
    int b = (int)((xv[r] - XMIN) * BINW_INV);
    b = b < 0 ? 0 : (b > NBIN - 1 ? NBIN - 1 : b);
    bn[r] = b;
    atomicAdd(&hist[b], 1);
  }
  __syncthreads();                                    // B2
  if (t < 64) {
    // wave 0: barrier-free shfl scan over 150 bins (3 chunks of 64)
    int h0 = hist[t], h1 = hist[t + 64];
    int h2 = (t < NBIN - 128) ? hist[t + 128] : 0;
    int v0 = h0, v1 = h1, v2 = h2;
#pragma unroll
    for (int off = 1; off < 64; off <<= 1) {
      int a0 = __shfl_up(v0, off);
      int a1 = __shfl_up(v1, off);
      int a2 = __shfl_up(v2, off);
      if (t >= off) { v0 += a0; v1 += a1; v2 += a2; }
    }
    int tot0 = __shfl(v0, 63), tot1 = __shfl(v1, 63);
    int s0 = v0 - h0;                  // exclusive starts
    int s1 = tot0 + v1 - h1;
    int s2 = tot0 + tot1 + v2 - h2;
    bst[t] = s0;        ofs[t] = s0;
    bst[t + 64] = s1;   ofs[t + 64] = s1;
    if (t < NBIN - 128) { bst[t + 128] = s2; ofs[t + 128] = s2; }
    if (t == 0) bst[NBIN] = NPTS;
  } else if (t < 128) {
    // wave 1 (concurrent with scan): softmax over K=64 logits + params
    int k = t - 64;
    float l = logits[k];
    float m = l;
#pragma unroll
    for (int off = 32; off > 0; off >>= 1) m = fmaxf(m, __shfl_xor(m, off));
    float e = expf(l - m);
    float ssum = e;
#pragma unroll
    for (int off = 32; off > 0; off >>= 1) ssum += __shfl_xor(ssum, off);
    float w = e / ssum;
    float var = expf(log_vars[k]);
    sa[k] = w * rsqrtf(2.0f * (float)M_PI * var);   // amplitude
    sq[k] = 0.72134752044448170368f / var;          // 0.5*log2(e)/var
    smn[k] = means[k];
  }
  __syncthreads();                                    // B3
#pragma unroll
  for (int r = 0; r < 8; ++r) {
    int pos = atomicAdd(&ofs[bn[r]], 1);
    xs[pos] = xv[r];
  }
  __syncthreads();                                    // B4

  // ---- phase 2: windowed KDE + mixture pdf + MSE, all from LDS ----
  const float inv_norm = 1.0f / (2.50662827463100050242f * 64.0f);
  const float C = 8192.0f * 1.44269504088896340736f;  // 8192*log2(e)
  const int lane = t & 63;
  const int wv = t >> 6;
  const int gw = blockIdx.x * 16 + wv;   // 4096 waves, 2 sorted positions each
  // lane k owns mixture component k (K = wave size = 64)
  const float sal = sa[lane], sql = sq[lane], sml = smn[lane];

  float vsum = 0.0f;
#pragma unroll
  for (int r = 0; r < 2; ++r) {
    const int p = gw + r * 4096;     // pair left-half/right-half quantiles
    const float u = xs[p];           // LDS broadcast
    int b = (int)((u - XMIN) * BINW_INV);
    b = b < 0 ? 0 : (b > NBIN - 1 ? NBIN - 1 : b);
    const int j0 = bst[b > 0 ? b - 1 : 0];
    const int j1 = bst[(b + 2) > NBIN ? NBIN : (b + 2)];
    // windowed KDE: lanes split the neighbor list (stride-1 -> 2 lanes/bank, free)
    float acc = 0.0f;
    for (int j = j0 + lane; j < j1; j += 64) {
      float d = u - xs[j];                // subtract-first: matches ref rounding
      acc += fexp2(-(C * d) * d);
    }
    // mixture: one component per lane
    float dm = u - sml;
    float mixl = sal * fexp2(-(sql * dm) * dm);
    // joint butterfly reduce (all lanes end with the wave sums)
#pragma unroll
    for (int off = 32; off > 0; off >>= 1) {
      acc += __shfl_xor(acc, off);
      mixl += __shfl_xor(mixl, off);
    }
    float diff = mixl - acc * inv_norm;
    vsum += diff * diff;
  }
  if (lane == 0) wsum[wv] = vsum;
  __syncthreads();                                    // B5
  if (t == 0) {
    float v = 0.f;
#pragma unroll
    for (int i = 0; i < 16; ++i) v += wsum[i];
    ws[blockIdx.x] = v;                // per-block partial (overwrites poison)
  }

  cg::this_grid().sync();

  // block 0: deterministic tree reduce of 256 partials -> out
  if (blockIdx.x == 0 && t < 64) {
    float v = ws[t] + ws[t + 64] + ws[t + 128] + ws[t + 192];
#pragma unroll
    for (int off = 32; off > 0; off >>= 1) v += __shfl_xor(v, off);
    if (t == 0) out[0] = v;
  }
}

extern "C" void kernel_launch(void* const* d_in, const int* in_sizes, int n_in,
                              void* d_out, int out_size, void* d_ws, size_t ws_size,
                              hipStream_t stream) {
  const float* x     = (const float*)d_in[0];
  const float* wl    = (const float*)d_in[1];
  const float* means = (const float*)d_in[2];
  const float* lv    = (const float*)d_in[3];
  float* out = (float*)d_out;
  float* ws  = (float*)d_ws;

  void* args[] = {(void*)&x, (void*)&wl, (void*)&means, (void*)&lv,
                  (void*)&ws, (void*)&out};
  hipLaunchCooperativeKernel((const void*)gmm_kernel, dim3(NBLK), dim3(NTHR),
                             args, 0, stream);
}

// Round 5
// 78.758 us; speedup vs baseline: 1.3213x; 1.3213x over previous
//
#include <hip/hip_runtime.h>
#include <math.h>

#ifndef M_PI
#define M_PI 3.14159265358979323846
#endif

#define NPTS 8192
#define KCOMP 64
#define NBIN 150          // bins of width 0.08 over [-6, 6]
#define XMIN -6.0f
#define BINW_INV 12.5f    // 1/0.08
#define BINCAP 512        // max points/bin; expected max ~261 (9.7 sigma margin)
// kern = exp(-8192 d^2): underflows to 0.0f for d > 0.112; at d=0.08 it is
// 1.8e-23 (< 1 ulp of the per-point sum). +-1-bin windowing omits only pairs
// with d > 0.08 -> numerically exact vs the f32 reference.
//
// Round-5 design (post-mortems: coop launch +35us; per-block redundant sort
// ~10us): bin-compact ONCE in parallel (D1: 150 blocks, ballot/popc compaction,
// atomic-free, also zeroes out + softmax params -> no memset dispatch), then a
// tiny windowed-eval kernel (D2) reads the L2-resident bin lists. 2 dispatches,
// both ~1us class.

// ws float-index layout
#define WS_CNT  (NBIN * BINCAP)        // 150 ints (bit-stored in float ws)
#define WS_PAR  (WS_CNT + 256)         // sa[64], sq[64], smn[64]

// Single-instruction hardware exp2 (v_exp_f32).
__device__ __forceinline__ float fexp2(float a) {
#if __has_builtin(__builtin_amdgcn_exp2f)
  return __builtin_amdgcn_exp2f(a);
#else
  float r;
  asm("v_exp_f32 %0, %1" : "=v"(r) : "v"(a));
  return r;
#endif
}

__device__ __forceinline__ int binof(float v) {
  int b = (int)((v - XMIN) * BINW_INV);
  return b < 0 ? 0 : (b > NBIN - 1 ? NBIN - 1 : b);
}

// --- D1: per-bin compaction (150 blocks x 256 thr), atomic-free ------------
// Wave w of block b scans its contiguous 2048-elem segment of x (held in 8
// float4 regs), counts bin-b members via ballot, cross-wave exclusive scan
// (1 barrier), then writes its members compacted to ws[b*BINCAP + ...].
__global__ __launch_bounds__(256) void bin_compact_kernel(
    const float* __restrict__ x,
    const float* __restrict__ logits,
    const float* __restrict__ means,
    const float* __restrict__ log_vars,
    float* __restrict__ ws,
    float* __restrict__ out) {
  const int t = threadIdx.x;
  const int lane = t & 63;
  const int wv = t >> 6;
  const int b = blockIdx.x;
  __shared__ int wofs[4];

  const float4* x4 = reinterpret_cast<const float4*>(x);
  float4 vx[8];
#pragma unroll
  for (int r = 0; r < 8; ++r) vx[r] = x4[wv * 512 + r * 64 + lane];

  // pass 1: count this wave's bin-b members
  int wcnt = 0;
#pragma unroll
  for (int r = 0; r < 8; ++r) {
    wcnt += __popcll(__ballot(binof(vx[r].x) == b));
    wcnt += __popcll(__ballot(binof(vx[r].y) == b));
    wcnt += __popcll(__ballot(binof(vx[r].z) == b));
    wcnt += __popcll(__ballot(binof(vx[r].w) == b));
  }
  if (lane == 0) wofs[wv] = wcnt;
  __syncthreads();
  int base = 0;
#pragma unroll
  for (int w = 0; w < 4; ++w) base += (w < wv) ? wofs[w] : 0;
  const int total = wofs[0] + wofs[1] + wofs[2] + wofs[3];

  // pass 2: compacted writes (order within a bin is irrelevant for the sums)
  const unsigned long long ltmask = (1ULL << lane) - 1ULL;
  float* dst = ws + b * BINCAP;
#pragma unroll
  for (int r = 0; r < 8; ++r) {
    float4 v = vx[r];
    {
      unsigned long long m = __ballot(binof(v.x) == b);
      int idx = base + __popcll(m & ltmask);
      if ((binof(v.x) == b) && idx < BINCAP) dst[idx] = v.x;
      base += __popcll(m);
    }
    {
      unsigned long long m = __ballot(binof(v.y) == b);
      int idx = base + __popcll(m & ltmask);
      if ((binof(v.y) == b) && idx < BINCAP) dst[idx] = v.y;
      base += __popcll(m);
    }
    {
      unsigned long long m = __ballot(binof(v.z) == b);
      int idx = base + __popcll(m & ltmask);
      if ((binof(v.z) == b) && idx < BINCAP) dst[idx] = v.z;
      base += __popcll(m);
    }
    {
      unsigned long long m = __ballot(binof(v.w) == b);
      int idx = base + __popcll(m & ltmask);
      if ((binof(v.w) == b) && idx < BINCAP) dst[idx] = v.w;
      base += __popcll(m);
    }
  }
  if (t == 0)
    reinterpret_cast<int*>(ws)[WS_CNT + b] = total > BINCAP ? BINCAP : total;

  // block 0 extras: zero out; softmax over K=64 logits + component params
  if (b == 0) {
    if (t == 64) out[0] = 0.0f;
    if (t < KCOMP) {
      float l = logits[t];
      float m = l;
#pragma unroll
      for (int off = 32; off > 0; off >>= 1) m = fmaxf(m, __shfl_xor(m, off));
      float e = expf(l - m);
      float ssum = e;
#pragma unroll
      for (int off = 32; off > 0; off >>= 1) ssum += __shfl_xor(ssum, off);
      float w = e / ssum;
      float var = expf(log_vars[t]);
      ws[WS_PAR + t]       = w * rsqrtf(2.0f * (float)M_PI * var);  // amplitude
      ws[WS_PAR + 64 + t]  = 0.72134752044448170368f / var;         // 0.5*log2e/var
      ws[WS_PAR + 128 + t] = means[t];
    }
  }
}

// --- D2: windowed KDE + mixture pdf + MSE (256 blocks x 256 thr) -----------
// Wave owns 8 points; lanes split each point's +-1-bin neighbor lists
// (L2-resident, coalesced). Lane k also owns mixture component k.
__global__ __launch_bounds__(256) void kde_final_kernel(
    const float* __restrict__ x,
    const float* __restrict__ ws,
    float* __restrict__ out) {
  const int t = threadIdx.x;
  const int lane = t & 63;
  const int wv = t >> 6;
  const float inv_norm = 1.0f / (2.50662827463100050242f * 64.0f);
  const float C = 8192.0f * 1.44269504088896340736f;  // 8192*log2(e)

  const float* par = ws + WS_PAR;
  const float sal = par[lane];
  const float sql = par[64 + lane];
  const float sml = par[128 + lane];
  const int* cnt = reinterpret_cast<const int*>(ws) + WS_CNT;

  float vsum = 0.0f;
  const int p0 = blockIdx.x * 32 + wv * 8;
#pragma unroll
  for (int r = 0; r < 8; ++r) {
    const float u = x[p0 + r];          // wave-uniform load, L2-hot
    const int b = binof(u);
    const int lo = b > 0 ? b - 1 : 0;
    const int hi = b < NBIN - 1 ? b + 1 : NBIN - 1;
    float acc = 0.0f;
    for (int bb = lo; bb <= hi; ++bb) {
      const int c = cnt[bb];
      const float* lst = ws + bb * BINCAP;
      for (int j = lane; j < c; j += 64) {
        float d = u - lst[j];           // subtract-first: matches ref rounding
        acc += fexp2(-(C * d) * d);
      }
    }
    float dm = u - sml;
    float mixl = sal * fexp2(-(sql * dm) * dm);
#pragma unroll
    for (int off = 32; off > 0; off >>= 1) {
      acc += __shfl_xor(acc, off);
      mixl += __shfl_xor(mixl, off);
    }
    float diff = mixl - acc * inv_norm;
    vsum += diff * diff;
  }
  __shared__ float wsum[4];
  if (lane == 0) wsum[wv] = vsum;
  __syncthreads();
  if (t == 0) atomicAdd(out, (wsum[0] + wsum[1]) + (wsum[2] + wsum[3]));
}

extern "C" void kernel_launch(void* const* d_in, const int* in_sizes, int n_in,
                              void* d_out, int out_size, void* d_ws, size_t ws_size,
                              hipStream_t stream) {
  const float* x     = (const float*)d_in[0];
  const float* wl    = (const float*)d_in[1];
  const float* means = (const float*)d_in[2];
  const float* lv    = (const float*)d_in[3];
  float* out = (float*)d_out;
  float* ws  = (float*)d_ws;   // uses ~309 KB

  bin_compact_kernel<<<NBIN, 256, 0, stream>>>(x, wl, means, lv, ws, out);
  kde_final_kernel<<<NPTS / 32, 256, 0, stream>>>(x, ws, out);
}

// Round 6
// 67.600 us; speedup vs baseline: 1.5393x; 1.1651x over previous
//
#include <hip/hip_runtime.h>
#include <math.h>

#ifndef M_PI
#define M_PI 3.14159265358979323846
#endif

#define NPTS 8192
#define KCOMP 64
#define NBIN 150          // bins of width 0.08 over [-6, 6]
#define XMIN -6.0f
#define BINW_INV 12.5f    // 1/0.08
#define NBLK 256          // 1 block per CU (co-resident even if packed 2/CU)
#define NTHR 1024         // 16 waves
#define MAGIC 0x1357BEEFu
// kern = exp(-8192 d^2): underflows to 0.0f for d > 0.112; at d=0.08 it is
// 1.8e-23 (< 1 ulp of the per-point sum). +-1-bin windowing omits only pairs
// with d > 0.08 -> numerically exact vs the f32 reference.
//
// Round-6 design. Time model from R0..R5: controllable cost ~= 10us per
// dispatch + kernel time (kernels are <=8us). So: ONE plain dispatch.
// Zero-init under ws-poisoning is solved with a magic-tagged handshake:
// block b stores partial (RELAXED) then tag=MAGIC (RELEASE) into ws; block
// 255's lanes acquire-spin on the 256 tags, reduce, single plain store to
// out. No memset dispatch, no global atomicAdd, no coop launch (+35us, R4).
// Compute body = R3/R4 proven structure: per-block redundant counting sort
// of all 8192 pts into LDS (32KB), windowed KDE at 16 waves/block from LDS.

// Single-instruction hardware exp2 (v_exp_f32).
__device__ __forceinline__ float fexp2(float a) {
#if __has_builtin(__builtin_amdgcn_exp2f)
  return __builtin_amdgcn_exp2f(a);
#else
  float r;
  asm("v_exp_f32 %0, %1" : "=v"(r) : "v"(a));
  return r;
#endif
}

__global__ __launch_bounds__(NTHR) void gmm_kernel(
    const float* __restrict__ x,
    const float* __restrict__ logits,
    const float* __restrict__ means,
    const float* __restrict__ log_vars,
    float* __restrict__ ws,
    float* __restrict__ out) {
  __shared__ alignas(16) float xs[NPTS];   // bin-sorted, UNSCALED (32 KB)
  __shared__ int hist[NBIN];
  __shared__ int ofs[NBIN];
  __shared__ int bst[NBIN + 2];
  __shared__ float sa[KCOMP], sq[KCOMP], smn[KCOMP];
  __shared__ float wsum[16];

  const int t = threadIdx.x;

  // ---- phase 1: block-local counting sort of ALL 8192 points ----
  const float4* x4 = reinterpret_cast<const float4*>(x);
  float4 va = x4[t];           // floats [0, 4096)
  float4 vb = x4[t + NTHR];    // floats [4096, 8192)
  float xv[8] = {va.x, va.y, va.z, va.w, vb.x, vb.y, vb.z, vb.w};
  int bn[8];
  if (t < NBIN) hist[t] = 0;
  __syncthreads();                                    // B1
#pragma unroll
  for (int r = 0; r < 8; ++r) {
    int b = (int)((xv[r] - XMIN) * BINW_INV);
    b = b < 0 ? 0 : (b > NBIN - 1 ? NBIN - 1 : b);
    bn[r] = b;
    atomicAdd(&hist[b], 1);
  }
  __syncthreads();                                    // B2
  if (t < 64) {
    // wave 0: barrier-free shfl scan over 150 bins (3 chunks of 64)
    int h0 = hist[t], h1 = hist[t + 64];
    int h2 = (t < NBIN - 128) ? hist[t + 128] : 0;
    int v0 = h0, v1 = h1, v2 = h2;
#pragma unroll
    for (int off = 1; off < 64; off <<= 1) {
      int a0 = __shfl_up(v0, off);
      int a1 = __shfl_up(v1, off);
      int a2 = __shfl_up(v2, off);
      if (t >= off) { v0 += a0; v1 += a1; v2 += a2; }
    }
    int tot0 = __shfl(v0, 63), tot1 = __shfl(v1, 63);
    int s0 = v0 - h0;                  // exclusive starts
    int s1 = tot0 + v1 - h1;
    int s2 = tot0 + tot1 + v2 - h2;
    bst[t] = s0;        ofs[t] = s0;
    bst[t + 64] = s1;   ofs[t + 64] = s1;
    if (t < NBIN - 128) { bst[t + 128] = s2; ofs[t + 128] = s2; }
    if (t == 0) bst[NBIN] = NPTS;
  } else if (t < 128) {
    // wave 1 (concurrent with scan): softmax over K=64 logits + params
    int k = t - 64;
    float l = logits[k];
    float m = l;
#pragma unroll
    for (int off = 32; off > 0; off >>= 1) m = fmaxf(m, __shfl_xor(m, off));
    float e = expf(l - m);
    float ssum = e;
#pragma unroll
    for (int off = 32; off > 0; off >>= 1) ssum += __shfl_xor(ssum, off);
    float w = e / ssum;
    float var = expf(log_vars[k]);
    sa[k] = w * rsqrtf(2.0f * (float)M_PI * var);   // amplitude
    sq[k] = 0.72134752044448170368f / var;          // 0.5*log2(e)/var
    smn[k] = means[k];
  }
  __syncthreads();                                    // B3
#pragma unroll
  for (int r = 0; r < 8; ++r) {
    int pos = atomicAdd(&ofs[bn[r]], 1);
    xs[pos] = xv[r];
  }
  __syncthreads();                                    // B4

  // ---- phase 2: windowed KDE + mixture pdf + MSE, all from LDS ----
  const float inv_norm = 1.0f / (2.50662827463100050242f * 64.0f);
  const float C = 8192.0f * 1.44269504088896340736f;  // 8192*log2(e)
  const int lane = t & 63;
  const int wv = t >> 6;
  const int gw = blockIdx.x * 16 + wv;   // 4096 waves, 2 sorted positions each
  // lane k owns mixture component k (K = wave size = 64)
  const float sal = sa[lane], sql = sq[lane], sml = smn[lane];

  float vsum = 0.0f;
#pragma unroll
  for (int r = 0; r < 2; ++r) {
    const int p = gw + r * 4096;     // pair left-half/right-half quantiles
    const float u = xs[p];           // LDS broadcast
    int b = (int)((u - XMIN) * BINW_INV);
    b = b < 0 ? 0 : (b > NBIN - 1 ? NBIN - 1 : b);
    const int j0 = bst[b > 0 ? b - 1 : 0];
    const int j1 = bst[(b + 2) > NBIN ? NBIN : (b + 2)];
    // windowed KDE: lanes split the neighbor list (stride-1 -> 2 lanes/bank)
    float acc = 0.0f;
    for (int j = j0 + lane; j < j1; j += 64) {
      float d = u - xs[j];                // subtract-first: matches ref rounding
      acc += fexp2(-(C * d) * d);
    }
    // mixture: one component per lane
    float dm = u - sml;
    float mixl = sal * fexp2(-(sql * dm) * dm);
    // joint butterfly reduce (all lanes end with the wave sums)
#pragma unroll
    for (int off = 32; off > 0; off >>= 1) {
      acc += __shfl_xor(acc, off);
      mixl += __shfl_xor(mixl, off);
    }
    float diff = mixl - acc * inv_norm;
    vsum += diff * diff;
  }
  if (lane == 0) wsum[wv] = vsum;
  __syncthreads();                                    // B5

  // ---- phase 3: poison-immune cross-block reduction (no init needed) ----
  float* part = ws;                                   // ws_f[0..256)
  unsigned* tag = reinterpret_cast<unsigned*>(ws) + 256;  // ws_u[256..512)
  if (t == 0) {
    float p = 0.f;
#pragma unroll
    for (int i = 0; i < 16; ++i) p += wsum[i];
    __hip_atomic_store(&part[blockIdx.x], p, __ATOMIC_RELAXED,
                       __HIP_MEMORY_SCOPE_AGENT);
    __hip_atomic_store(&tag[blockIdx.x], MAGIC, __ATOMIC_RELEASE,
                       __HIP_MEMORY_SCOPE_AGENT);
  }
  if (blockIdx.x == NBLK - 1) {        // block-uniform branch: barriers legal
    __syncthreads();                                  // B6 (wsum reuse fence)
    float v = 0.f;
    if (t < NBLK) {
      while (__hip_atomic_load(&tag[t], __ATOMIC_ACQUIRE,
                               __HIP_MEMORY_SCOPE_AGENT) != MAGIC)
        __builtin_amdgcn_s_sleep(8);
      v = __hip_atomic_load(&part[t], __ATOMIC_RELAXED,
                            __HIP_MEMORY_SCOPE_AGENT);
    }
#pragma unroll
    for (int off = 32; off > 0; off >>= 1) v += __shfl_xor(v, off);
    if (lane == 0) wsum[wv] = v;       // waves 4..15 contribute 0
    __syncthreads();                                  // B7
    if (t == 0) {
      float s = 0.f;
#pragma unroll
      for (int i = 0; i < 16; ++i) s += wsum[i];
      out[0] = s;                      // single plain store: poison-immune
    }
  }
}

extern "C" void kernel_launch(void* const* d_in, const int* in_sizes, int n_in,
                              void* d_out, int out_size, void* d_ws, size_t ws_size,
                              hipStream_t stream) {
  const float* x     = (const float*)d_in[0];
  const float* wl    = (const float*)d_in[1];
  const float* means = (const float*)d_in[2];
  const float* lv    = (const float*)d_in[3];
  float* out = (float*)d_out;
  float* ws  = (float*)d_ws;   // uses 2 KB (256 partials + 256 tags)

  gmm_kernel<<<NBLK, NTHR, 0, stream>>>(x, wl, means, lv, ws, out);
}

// Round 7
// 66.957 us; speedup vs baseline: 1.5541x; 1.0096x over previous
//
#include <hip/hip_runtime.h>
#include <math.h>

#ifndef M_PI
#define M_PI 3.14159265358979323846
#endif

#define NPTS 8192
#define KCOMP 64
#define NBIN 150          // bins of width 0.08 over [-6, 6]
#define XMIN -6.0f
#define BINW_INV 12.5f    // 1/0.08
#define NBLK 256          // 1 block per CU -> trivially co-resident
#define NTHR 1024         // 16 waves
#define MAGIC 0x1357BEEFu
// kern = exp(-8192 d^2): underflows to 0.0f for d > 0.112; at d=0.08 it is
// 1.8e-23 (< 1 ulp of the per-point sum). +-1-bin windowing omits only pairs
// with d > 0.08 -> numerically exact vs the f32 reference. Window edges are
// extended to 16B alignment: the <=3 extra elements per side are >=1 full bin
// away (kern <= 2e-23) and vanish in the f32 sum, exactly as they do in the
// reference's own summation.
//
// Time model (R0-R6 probes): dur = 39.4us ws-poison fill (harness, fixed)
// + ~22us fixed window overhead + sum(kernel + ~1us/dispatch). Dispatches
// are cheap (~1us, R3 vs R6); coop launch is +35us (R4); 2-kernel split with
// a latency-bound eval is +11 (R5). So: ONE plain dispatch, minimize kernel.
// R7 cuts vs R6 (5.2us kernel): (1) eval reads ds_read_b128 (13 b32 iters ->
// 4 b128 iters/point); (2) single LDS-atomic round - pass-1 atomicAdd return
// IS the within-bin rank, scatter = bst[bin]+rank (no ofs array); (3) param
// loads hoisted to kernel top (off the scan critical path); (4) final reduce
// by wave 0 of block 255 only (2 fewer barriers).

// Single-instruction hardware exp2 (v_exp_f32).
__device__ __forceinline__ float fexp2(float a) {
#if __has_builtin(__builtin_amdgcn_exp2f)
  return __builtin_amdgcn_exp2f(a);
#else
  float r;
  asm("v_exp_f32 %0, %1" : "=v"(r) : "v"(a));
  return r;
#endif
}

__global__ __launch_bounds__(NTHR) void gmm_kernel(
    const float* __restrict__ x,
    const float* __restrict__ logits,
    const float* __restrict__ means,
    const float* __restrict__ log_vars,
    float* __restrict__ ws,
    float* __restrict__ out) {
  __shared__ alignas(16) float xs[NPTS];   // bin-sorted, UNSCALED (32 KB)
  __shared__ int hist[NBIN];
  __shared__ int bst[NBIN + 2];
  __shared__ float sa[KCOMP], sq[KCOMP], smn[KCOMP];
  __shared__ float wsum[16];

  const int t = threadIdx.x;

  // ---- issue ALL global loads up front (one miss round, overlapped) ----
  const float4* x4 = reinterpret_cast<const float4*>(x);
  float4 va = x4[t];           // floats [0, 4096)
  float4 vb = x4[t + NTHR];    // floats [4096, 8192)
  float pl = 0.f, plv = 0.f, pmn = 0.f;
  if (t >= 64 && t < 128) {    // wave 1 fetches softmax params
    pl  = logits[t - 64];
    plv = log_vars[t - 64];
    pmn = means[t - 64];
  }
  if (t < NBIN) hist[t] = 0;
  __syncthreads();                                    // B1

  // ---- phase 1: bin + rank via ONE atomic round ----
  float xv[8] = {va.x, va.y, va.z, va.w, vb.x, vb.y, vb.z, vb.w};
  int bn[8], rk[8];
#pragma unroll
  for (int r = 0; r < 8; ++r) {
    int b = (int)((xv[r] - XMIN) * BINW_INV);
    b = b < 0 ? 0 : (b > NBIN - 1 ? NBIN - 1 : b);
    bn[r] = b;
    rk[r] = atomicAdd(&hist[b], 1);   // return value = within-bin rank
  }
  // wave 1: softmax over K=64 logits + component params (needs only the
  // hoisted loads -> runs before B2, off the scan critical path)
  if (t >= 64 && t < 128) {
    int k = t - 64;
    float m = pl;
#pragma unroll
    for (int off = 32; off > 0; off >>= 1) m = fmaxf(m, __shfl_xor(m, off));
    float e = expf(pl - m);
    float ssum = e;
#pragma unroll
    for (int off = 32; off > 0; off >>= 1) ssum += __shfl_xor(ssum, off);
    float w = e / ssum;
    float var = expf(plv);
    sa[k] = w * rsqrtf(2.0f * (float)M_PI * var);   // amplitude
    sq[k] = 0.72134752044448170368f / var;          // 0.5*log2(e)/var
    smn[k] = pmn;
  }
  __syncthreads();                                    // B2
  if (t < 64) {
    // wave 0: barrier-free shfl scan over 150 bins (3 chunks of 64)
    int h0 = hist[t], h1 = hist[t + 64];
    int h2 = (t < NBIN - 128) ? hist[t + 128] : 0;
    int v0 = h0, v1 = h1, v2 = h2;
#pragma unroll
    for (int off = 1; off < 64; off <<= 1) {
      int a0 = __shfl_up(v0, off);
      int a1 = __shfl_up(v1, off);
      int a2 = __shfl_up(v2, off);
      if (t >= off) { v0 += a0; v1 += a1; v2 += a2; }
    }
    int tot0 = __shfl(v0, 63), tot1 = __shfl(v1, 63);
    bst[t] = v0 - h0;                          // exclusive starts
    bst[t + 64] = tot0 + v1 - h1;
    if (t < NBIN - 128) bst[t + 128] = tot0 + tot1 + v2 - h2;
    if (t == 0) bst[NBIN] = NPTS;
  }
  __syncthreads();                                    // B3
#pragma unroll
  for (int r = 0; r < 8; ++r)
    xs[bst[bn[r]] + rk[r]] = xv[r];   // scatter: no second atomic round
  __syncthreads();                                    // B4

  // ---- phase 2: windowed KDE (b128 reads) + mixture + MSE ----
  const float inv_norm = 1.0f / (2.50662827463100050242f * 64.0f);
  const float C = 8192.0f * 1.44269504088896340736f;  // 8192*log2(e)
  const int lane = t & 63;
  const int wv = t >> 6;
  const int gw = blockIdx.x * 16 + wv;   // 4096 waves, 2 sorted positions each
  const float sal = sa[lane], sql = sq[lane], sml = smn[lane];
  const float4* xs4 = reinterpret_cast<const float4*>(xs);

  float vsum = 0.0f;
#pragma unroll
  for (int r = 0; r < 2; ++r) {
    const int p = gw + r * 4096;     // pair left-half/right-half quantiles
    const float u = xs[p];           // LDS broadcast
    int b = (int)((u - XMIN) * BINW_INV);
    b = b < 0 ? 0 : (b > NBIN - 1 ? NBIN - 1 : b);
    const int q0 = bst[b > 0 ? b - 1 : 0] >> 2;                     // floor/16B
    const int q1 = (bst[(b + 2) > NBIN ? NBIN : (b + 2)] + 3) >> 2; // ceil/16B
    float acc0 = 0.f, acc1 = 0.f;
    for (int q = q0 + lane; q < q1; q += 64) {
      float4 v = xs4[q];             // ds_read_b128, conflict-free
      float d0 = u - v.x, d1 = u - v.y, d2 = u - v.z, d3 = u - v.w;
      acc0 += fexp2(-(C * d0) * d0);
      acc1 += fexp2(-(C * d1) * d1);
      acc0 += fexp2(-(C * d2) * d2);
      acc1 += fexp2(-(C * d3) * d3);
    }
    float acc = acc0 + acc1;
    // mixture: one component per lane
    float dm = u - sml;
    float mixl = sal * fexp2(-(sql * dm) * dm);
    // joint butterfly reduce (all lanes end with the wave sums)
#pragma unroll
    for (int off = 32; off > 0; off >>= 1) {
      acc += __shfl_xor(acc, off);
      mixl += __shfl_xor(mixl, off);
    }
    float diff = mixl - acc * inv_norm;
    vsum += diff * diff;
  }
  if (lane == 0) wsum[wv] = vsum;
  __syncthreads();                                    // B5

  // ---- phase 3: poison-immune cross-block reduction (no init needed) ----
  float* part = ws;                                   // ws_f[0..256)
  unsigned* tag = reinterpret_cast<unsigned*>(ws) + 256;  // ws_u[256..512)
  if (t == 0) {
    float p = 0.f;
#pragma unroll
    for (int i = 0; i < 16; ++i) p += wsum[i];
    __hip_atomic_store(&part[blockIdx.x], p, __ATOMIC_RELAXED,
                       __HIP_MEMORY_SCOPE_AGENT);
    __hip_atomic_store(&tag[blockIdx.x], MAGIC, __ATOMIC_RELEASE,
                       __HIP_MEMORY_SCOPE_AGENT);
  }
  if (blockIdx.x == NBLK - 1 && t < 64) {  // wave 0 only: 4 partials/lane
    float v = 0.f;
#pragma unroll
    for (int k = 0; k < 4; ++k) {
      const int idx = t + k * 64;
      while (__hip_atomic_load(&tag[idx], __ATOMIC_ACQUIRE,
                               __HIP_MEMORY_SCOPE_AGENT) != MAGIC)
        __builtin_amdgcn_s_sleep(2);
      v += __hip_atomic_load(&part[idx], __ATOMIC_RELAXED,
                             __HIP_MEMORY_SCOPE_AGENT);
    }
#pragma unroll
    for (int off = 32; off > 0; off >>= 1) v += __shfl_xor(v, off);
    if (t == 0) out[0] = v;              // single plain store: poison-immune
  }
}

extern "C" void kernel_launch(void* const* d_in, const int* in_sizes, int n_in,
                              void* d_out, int out_size, void* d_ws, size_t ws_size,
                              hipStream_t stream) {
  const float* x     = (const float*)d_in[0];
  const float* wl    = (const float*)d_in[1];
  const float* means = (const float*)d_in[2];
  const float* lv    = (const float*)d_in[3];
  float* out = (float*)d_out;
  float* ws  = (float*)d_ws;   // uses 2 KB (256 partials + 256 tags)

  gmm_kernel<<<NBLK, NTHR, 0, stream>>>(x, wl, means, lv, ws, out);
}